// Round 13
// baseline (49.743 us; speedup 1.0000x reference)
//
#include <hip/hip_runtime.h>

#define KN      1024
#define FAN_IN  16
#define NSP     64
#define MAPB    (NSP * NSP)
#define THRESH  12

__device__ __forceinline__ float tanh_fast(float x) {
    float ax = fabsf(x);
    float e  = __expf(-2.0f * ax);
    float r  = 1.0f - 2.0f * e * __builtin_amdgcn_rcpf(1.0f + e);
    return copysignf(r, x);
}

// Full-wave DPP shifts; bound_ctrl=1 zeroes shifted-in edge lane = conv zero-pad
// at col 0 / col 63. Proven in R9/R10.
__device__ __forceinline__ float dpp_wshr1(float x) {  // lane L <- lane L-1
    return __int_as_float(__builtin_amdgcn_update_dpp(
        0, __float_as_int(x), 0x138, 0xF, 0xF, true));
}
__device__ __forceinline__ float dpp_wshl1(float x) {  // lane L <- lane L+1
    return __int_as_float(__builtin_amdgcn_update_dpp(
        0, __float_as_int(x), 0x130, 0xF, 0xF, true));
}

// 1 block = 1 node, 512 threads = 8 waves = {channel-group g 0..3} x {row-half h 0..1}.
// Wave: 4 channels x 32 output rows (lane = column), 32 register accumulators,
// 34 coalesced row-loads per channel (independent -> deep MLP), 2 DPP + <=9 FMA
// per input row. NO barriers in the main loop. One __syncthreads(), then 4-way
// cross-group LDS reduce + bias + tanh + store.
// R12 FIX vs R11: epilogue covers exactly MAPB=4096 elements (n<8, was n<16 ->
// OOB writes into node k+1's tile and OOB slab reads).
__global__ __launch_bounds__(512, 4) void decoder_kernel(
    const float* __restrict__ prev_outputs,      // [1024,64,64]
    const void*  __restrict__ prev_is_active,    // [1024] bool(1B) or int32 (sniffed)
    const int*   __restrict__ parent_indices,    // [1024,16]
    const float* __restrict__ Wt,                // [1024,16,3,3]
    const float* __restrict__ bias,              // [1024]
    float*       __restrict__ out)               // [1024*4096] + [1024] activity
{
    __shared__ float slab[8][32][NSP];           // 8 x 8 KB = 64 KB partials

    const int k    = blockIdx.x;
    const int tid  = threadIdx.x;
    const int lane = tid & 63;                   // column
    const int wv   = tid >> 6;                   // wave id
    const int g    = wv >> 1;                    // channel group 0..3
    const int h    = wv & 1;                     // row half 0..1

    // --- sniff flag encoding: numpy bool (1 byte) vs int32. Deterministic. ---
    bool bytemode = false;
    {
        const unsigned* sv = (const unsigned*)prev_is_active;
        #pragma unroll
        for (int i = 0; i < 16; ++i)
            if (sv[i] > 1u) bytemode = true;
    }

    // --- activity gate (uniform scalar work) ---
    const int* pidx = parent_indices + k * FAN_IN;
    int cnt = 0;
    #pragma unroll
    for (int i = 0; i < FAN_IN; ++i) {
        int p = pidx[i];
        int f;
        if (bytemode) f = (((const unsigned char*)prev_is_active)[p] != 0);
        else          f = (((const int*)prev_is_active)[p] != 0);
        cnt += f;
    }
    const bool active = (cnt >= THRESH);

    const size_t obase = (size_t)k * MAPB;
    if (tid == 0)
        out[(size_t)KN * MAPB + k] = active ? 1.0f : 0.0f;

    if (!active) {                   // uniform early-exit: barrier never reached
        float4 z = make_float4(0.f, 0.f, 0.f, 0.f);
        float4* o4 = (float4*)(out + obase);
        o4[tid]       = z;
        o4[tid + 512] = z;
        return;
    }

    // wave-uniform row-boundary machinery.
    // Input global rows for this half: gbase+j, j=0..33, gbase = h*32 - 1.
    // j=0 is OOB for h=0 (row -1); j=33 is OOB for h=1 (row 64). Value-masked.
    const int   gbase = h * 32 - 1;
    const float mT = (h == 1) ? 1.0f : 0.0f;     // row gbase valid?
    const float mB = (h == 0) ? 1.0f : 0.0f;     // row gbase+33 valid?
    const int   gT = (h == 1) ? 31 : 0;          // clamped row for j=0
    const int   gB = (h == 0) ? 32 : 63;         // clamped row for j=33

    const float* wbase = Wt + (size_t)k * FAN_IN * 9;

    float acc[32];
    #pragma unroll
    for (int a = 0; a < 32; ++a) acc[a] = 0.0f;

    #pragma unroll 1
    for (int cc = 0; cc < 4; ++cc) {
        const int ch = g * 4 + cc;
        const int p  = pidx[ch];                              // uniform -> s_load
        const float* __restrict__ src = prev_outputs + (size_t)p * MAPB + lane;

        // 34 independent coalesced loads (256 B/wave each)
        float row[34];
        row[0] = src[gT * NSP] * mT;
        #pragma unroll
        for (int j = 1; j <= 32; ++j) row[j] = src[(gbase + j) * NSP];
        row[33] = src[gB * NSP] * mB;

        const float* w = wbase + ch * 9;                      // uniform -> s_loads
        const float wl[3] = { w[0], w[3], w[6] };
        const float wc[3] = { w[1], w[4], w[7] };
        const float wr[3] = { w[2], w[5], w[8] };

        // input row gbase+j feeds local out rows a = j-t (t = weight row 0..2)
        #pragma unroll
        for (int j = 0; j < 34; ++j) {
            const float l = dpp_wshr1(row[j]);
            const float r = dpp_wshl1(row[j]);
            #pragma unroll
            for (int t = 0; t < 3; ++t) {
                const int a = j - t;
                if (a >= 0 && a < 32)
                    acc[a] = fmaf(wl[t], l,
                              fmaf(wc[t], row[j],
                               fmaf(wr[t], r, acc[a])));
            }
        }
    }

    // publish partials, single barrier, 4-way reduce + epilogue
    #pragma unroll
    for (int a = 0; a < 32; ++a) slab[wv][a][lane] = acc[a];

    __syncthreads();

    const float bk = bias[k];
    #pragma unroll
    for (int n = 0; n < 8; ++n) {                // 8 x 512 = 4096 = MAPB exactly
        const int i   = tid + n * 512;           // 0..4095
        const int r_  = i >> 6;                  // global out row 0..63
        const int col = i & 63;
        const int h2  = r_ >> 5;                 // 0..1
        const int a   = r_ & 31;
        const float s = slab[h2][a][col] + slab[2 + h2][a][col]
                      + slab[4 + h2][a][col] + slab[6 + h2][a][col];
        out[obase + (size_t)r_ * NSP + col] = tanh_fast(s + bk);
    }
}

extern "C" void kernel_launch(void* const* d_in, const int* in_sizes, int n_in,
                              void* d_out, int out_size, void* d_ws, size_t ws_size,
                              hipStream_t stream) {
    const float* prev_outputs   = (const float*)d_in[0];
    const void*  prev_is_active = d_in[1];
    const int*   parent_indices = (const int*)d_in[2];
    const float* Wt             = (const float*)d_in[3];
    const float* bias           = (const float*)d_in[4];
    float*       out            = (float*)d_out;

    decoder_kernel<<<dim3(KN), dim3(512), 0, stream>>>(
        prev_outputs, prev_is_active, parent_indices, Wt, bias, out);
}